// Round 1
// baseline (146.839 us; speedup 1.0000x reference)
//
#include <hip/hip_runtime.h>
#include <hip/hip_bf16.h>
#include <stdint.h>

#define NB 8
#define NS 1024
#define DM 768
#define NH 12
#define DH 64
#define NE 2304            // 3*DM
#define MTOT (NB*NS)       // 8192

typedef unsigned short u16;
typedef __attribute__((ext_vector_type(8))) __bf16 bf16x8;
typedef __attribute__((ext_vector_type(4))) float floatx4;

// ---- workspace layout (bytes) ----
#define WS_XB  0ull                    // x bf16 [8192][768]        12.6 MB
#define WS_WT  12582912ull             // w^T bf16 [2304][768]       3.5 MB
#define WS_QB  16121856ull             // Q bf16 [96][1024][64]     12.6 MB
#define WS_KB  28704768ull             // K bf16 [96][1024][64]     12.6 MB
#define WS_VT  41287680ull             // V^T bf16 [96][64][1024]   12.6 MB
                                       // total 53.9 MB

__device__ __forceinline__ u16 f2bf(float f) {
  union { float f; uint32_t u; } v; v.f = f;
  uint32_t r = (v.u + 0x7fffu + ((v.u >> 16) & 1u)) >> 16;   // RNE
  return (u16)r;
}

__device__ __forceinline__ void gload16(const void* g, void* l) {
  __builtin_amdgcn_global_load_lds(
      (const __attribute__((address_space(1))) void*)g,
      (__attribute__((address_space(3))) void*)l, 16, 0, 0);
}

// ---------------- convert x -> bf16 ----------------
__global__ void conv_x_kernel(const float4* __restrict__ x, u16* __restrict__ xb, int n4) {
  int i = blockIdx.x * blockDim.x + threadIdx.x;
  int stride = gridDim.x * blockDim.x;
  for (; i < n4; i += stride) {
    float4 v = x[i];
    ushort4 r;
    r.x = f2bf(v.x); r.y = f2bf(v.y); r.z = f2bf(v.z); r.w = f2bf(v.w);
    ((ushort4*)xb)[i] = r;
  }
}

// ---------------- transpose w [768][2304] f32 -> [2304][768] bf16 ----------------
__global__ void transpose_w_kernel(const float* __restrict__ w, u16* __restrict__ wt) {
  __shared__ float tile[32][33];
  const int e0 = blockIdx.x * 32, k0 = blockIdx.y * 32;
  const int tx = threadIdx.x, ty = threadIdx.y;   // block (32,8)
#pragma unroll
  for (int i = 0; i < 4; i++)
    tile[ty + i*8][tx] = w[(size_t)(k0 + ty + i*8) * NE + e0 + tx];
  __syncthreads();
#pragma unroll
  for (int i = 0; i < 4; i++)
    wt[(size_t)(e0 + ty + i*8) * DM + k0 + tx] = f2bf(tile[tx][ty + i*8]);
}

// ---------------- QKV GEMM: [8192x768]bf16 @ [768x2304] (B^T form) + bias,
//                  scatter into Q,K (bh,n,d) and V^T (bh,d,n) ----------------
__global__ __launch_bounds__(256) void qkv_gemm_kernel(
    const u16* __restrict__ xb, const u16* __restrict__ wt,
    const float* __restrict__ bias,
    u16* __restrict__ qb, u16* __restrict__ kb, u16* __restrict__ vtb) {
  __shared__ __align__(16) u16 a_lds[128 * 32];
  __shared__ __align__(16) u16 b_lds[128 * 32];
  const int t  = threadIdx.x;
  const int w  = t >> 6, l = t & 63;
  const int wr = w >> 1, wc = w & 1;
  const int lq = l & 15, lg = l >> 4;
  const int m0 = (int)(blockIdx.x % 64) * 128;
  const int n0 = (int)(blockIdx.x / 64) * 128;

  floatx4 z = {0.f, 0.f, 0.f, 0.f};
  floatx4 acc[4][4];
#pragma unroll
  for (int i = 0; i < 4; i++)
#pragma unroll
    for (int j = 0; j < 4; j++) acc[i][j] = z;

  // staging coords: row = i*64 + t/4, 16B-block col = (t&3) ^ swizzle((row>>1)&3)
  const int srow = t >> 2;
  const int scb  = (t & 3) ^ ((t >> 3) & 3);
  const u16* ga = xb + (size_t)m0 * DM + scb * 8;
  const u16* gb = wt + (size_t)n0 * DM + scb * 8;
  const int rswz = (lq >> 1) & 3;   // read-side swizzle

  for (int k0 = 0; k0 < DM; k0 += 32) {
#pragma unroll
    for (int i = 0; i < 2; i++) {
      gload16(ga + (size_t)(i*64 + srow) * DM + k0, (char*)a_lds + i*4096 + w*1024);
      gload16(gb + (size_t)(i*64 + srow) * DM + k0, (char*)b_lds + i*4096 + w*1024);
    }
    __syncthreads();   // drains vmcnt before barrier

    bf16x8 af[4], bfr[4];
#pragma unroll
    for (int i = 0; i < 4; i++)
      af[i] = *(const bf16x8*)((const char*)a_lds + (wr*64 + i*16 + lq)*64 + ((lg ^ rswz) * 16));
#pragma unroll
    for (int j = 0; j < 4; j++)
      bfr[j] = *(const bf16x8*)((const char*)b_lds + (wc*64 + j*16 + lq)*64 + ((lg ^ rswz) * 16));
#pragma unroll
    for (int i = 0; i < 4; i++)
#pragma unroll
      for (int j = 0; j < 4; j++)
        acc[i][j] = __builtin_amdgcn_mfma_f32_16x16x32_bf16(af[i], bfr[j], acc[i][j], 0, 0, 0);
    __syncthreads();   // reads done before next stage overwrites
  }

  // epilogue: C[m][n] = acc + bias[n]; scatter by (qkv,h,d); m -> (b,nn)
#pragma unroll
  for (int j = 0; j < 4; j++) {
    const int gn = n0 + wc*64 + j*16 + lq;
    const float bv = bias[gn];
    const int qkv = gn % 3;
    const int h   = gn / 192;
    const int d   = (gn % 192) / 3;
#pragma unroll
    for (int i = 0; i < 4; i++) {
      const int gmb = m0 + wr*64 + i*16 + lg*4;
#pragma unroll
      for (int r = 0; r < 4; r++) {
        const int gm = gmb + r;
        const int bb = gm >> 10, nn = gm & 1023;
        const int bh = bb * NH + h;
        const u16 val = f2bf(acc[i][j][r] + bv);
        if (qkv == 0)      qb[((size_t)bh * NS + nn) * DH + d] = val;
        else if (qkv == 1) kb[((size_t)bh * NS + nn) * DH + d] = val;
        else               vtb[((size_t)bh * DH + d) * NS + nn] = val;
      }
    }
  }
}

// ---------------- flash attention ----------------
// block = 256 (4 waves), each wave owns 32 q-rows; 64-key LDS stages.
// S^T = mfma(K, Q): lane holds S[key=4*lg+r][q=lq]  (swapped operands)
__global__ __launch_bounds__(256) void attn_kernel(
    const u16* __restrict__ qb, const u16* __restrict__ kb,
    const u16* __restrict__ vtb, float* __restrict__ out) {
  __shared__ __align__(16) u16 k_lds[64 * 64];
  __shared__ __align__(16) u16 v_lds[64 * 64];
  __shared__ __align__(16) u16 p_lds[4][16 * 40];   // per-wave P scratch, padded rows

  const int t = threadIdx.x, w = t >> 6, l = t & 63;
  const int bh = blockIdx.x >> 3, qblk = blockIdx.x & 7;
  const int bb = bh / NH, h = bh % NH;
  const int q0 = qblk * 128 + w * 32;
  const int lq = l & 15, lg = l >> 4;

  const float cscale = 0.03608439182435161f * 1.4426950408889634f;  // 768^-0.5 * log2(e)

  // Q fragments (B-operand of S^T mfma): lane holds Q[q=lq][d-slice]
  bf16x8 qf[2][2];
#pragma unroll
  for (int qt = 0; qt < 2; qt++) {
    const u16* qrow = qb + ((size_t)bh * NS + q0 + qt*16 + lq) * DH;
#pragma unroll
    for (int ds = 0; ds < 2; ds++)
      qf[qt][ds] = *(const bf16x8*)&qrow[lg*8 + ds*32];
  }

  float m2[2]   = {-1e30f, -1e30f};
  float lsum[2] = {0.f, 0.f};
  floatx4 z = {0.f, 0.f, 0.f, 0.f};
  floatx4 o[2][4];
#pragma unroll
  for (int qt = 0; qt < 2; qt++)
#pragma unroll
    for (int dt = 0; dt < 4; dt++) o[qt][dt] = z;

  // staging coords: row = i*32 + t/8 (128B rows), block = (t&7) ^ (row&7)
  const int srow = t >> 3;
  const int scb  = (t & 7) ^ ((t >> 3) & 7);

  for (int kt0 = 0; kt0 < 16; kt0++) {
    const int k0 = kt0 * 64;
    __syncthreads();   // all waves done reading previous tile
#pragma unroll
    for (int i = 0; i < 2; i++) {
      const int row = i*32 + srow;
      gload16(kb  + ((size_t)bh * NS + k0 + row) * DH + scb*8, (char*)k_lds + i*4096 + w*1024);
      gload16(vtb + ((size_t)bh * DH + row) * NS + k0 + scb*8, (char*)v_lds + i*4096 + w*1024);
    }
    __syncthreads();   // vmcnt drained by barrier

#pragma unroll
    for (int half = 0; half < 2; half++) {
#pragma unroll
      for (int qt = 0; qt < 2; qt++) {
        // S^T tile: 2x 16-key mfma, accumulate over d (K-dim)
        floatx4 st[2];
#pragma unroll
        for (int kt = 0; kt < 2; kt++) {
          st[kt] = z;
          const int row = half*32 + kt*16 + lq;     // key row in k_lds
#pragma unroll
          for (int ds = 0; ds < 2; ds++) {
            const int cb = (lg + ds*4) ^ (row & 7);
            bf16x8 kf = *(const bf16x8*)((const char*)k_lds + row*128 + cb*16);
            st[kt] = __builtin_amdgcn_mfma_f32_16x16x32_bf16(kf, qf[qt][ds], st[kt], 0, 0, 0);
          }
        }
        // online softmax (per q = lq; keys spread over regs + lane groups)
        float s2[8], mt = -1e30f;
#pragma unroll
        for (int kt = 0; kt < 2; kt++)
#pragma unroll
          for (int r = 0; r < 4; r++) {
            float v = st[kt][r] * cscale;
            s2[kt*4 + r] = v;
            mt = fmaxf(mt, v);
          }
        mt = fmaxf(mt, __shfl_xor(mt, 16));
        mt = fmaxf(mt, __shfl_xor(mt, 32));
        const float mnew = fmaxf(m2[qt], mt);
        const float corr = exp2f(m2[qt] - mnew);
        m2[qt] = mnew;
        float ps = 0.f;
        u16 pb[8];
#pragma unroll
        for (int e = 0; e < 8; e++) {
          float p = exp2f(s2[e] - mnew);
          ps += p;
          pb[e] = f2bf(p);
        }
        ps += __shfl_xor(ps, 16);
        ps += __shfl_xor(ps, 32);
        lsum[qt] = lsum[qt] * corr + ps;

        // P -> per-wave LDS scratch: row q=lq, col = local key
#pragma unroll
        for (int kt = 0; kt < 2; kt++) {
          ushort4 pk;
          pk.x = pb[kt*4+0]; pk.y = pb[kt*4+1]; pk.z = pb[kt*4+2]; pk.w = pb[kt*4+3];
          *(ushort4*)&p_lds[w][lq*40 + kt*16 + lg*4] = pk;
        }
        // rescale O (rows q' = 4*lg + r; corr lives at lane q')
        float cr[4];
#pragma unroll
        for (int r = 0; r < 4; r++) cr[r] = __shfl(corr, lg*4 + r);
#pragma unroll
        for (int dt = 0; dt < 4; dt++)
#pragma unroll
          for (int r = 0; r < 4; r++) o[qt][dt][r] *= cr[r];

        // PV: A = P[16q][32k] from scratch, B = V[32k][16d] from swizzled v_lds
        bf16x8 pa = *(const bf16x8*)&p_lds[w][lq*40 + lg*8];
#pragma unroll
        for (int dt = 0; dt < 4; dt++) {
          const int row = dt*16 + lq;               // d row in v_lds
          const int cb = (half*4 + lg) ^ (row & 7);
          bf16x8 vf = *(const bf16x8*)((const char*)v_lds + row*128 + cb*16);
          o[qt][dt] = __builtin_amdgcn_mfma_f32_16x16x32_bf16(pa, vf, o[qt][dt], 0, 0, 0);
        }
      }
    }
  }

  // normalize + write out[b][n][h*64 + d] (fp32)
#pragma unroll
  for (int qt = 0; qt < 2; qt++) {
    const float inv = 1.0f / lsum[qt];
    float ir[4];
#pragma unroll
    for (int r = 0; r < 4; r++) ir[r] = __shfl(inv, lg*4 + r);
#pragma unroll
    for (int dt = 0; dt < 4; dt++)
#pragma unroll
      for (int r = 0; r < 4; r++) {
        const int n = q0 + qt*16 + lg*4 + r;
        out[((size_t)bb * NS + n) * DM + h*DH + dt*16 + lq] = o[qt][dt][r] * ir[r];
      }
  }
}

extern "C" void kernel_launch(void* const* d_in, const int* in_sizes, int n_in,
                              void* d_out, int out_size, void* d_ws, size_t ws_size,
                              hipStream_t stream) {
  const float* x     = (const float*)d_in[0];
  const float* w_qkv = (const float*)d_in[1];
  const float* b_qkv = (const float*)d_in[2];
  float* out = (float*)d_out;
  char* ws = (char*)d_ws;

  u16* xb  = (u16*)(ws + WS_XB);
  u16* wt  = (u16*)(ws + WS_WT);
  u16* qb  = (u16*)(ws + WS_QB);
  u16* kb  = (u16*)(ws + WS_KB);
  u16* vtb = (u16*)(ws + WS_VT);

  conv_x_kernel<<<1024, 256, 0, stream>>>((const float4*)x, xb, MTOT * DM / 4);
  transpose_w_kernel<<<dim3(NE/32, DM/32), dim3(32, 8), 0, stream>>>(w_qkv, wt);
  qkv_gemm_kernel<<<64 * (NE/128), 256, 0, stream>>>(xb, wt, b_qkv, qb, kb, vtb);
  attn_kernel<<<(NB*NH) * (NS/128), 256, 0, stream>>>(qb, kb, vtb, out);
}

// Round 3
// 122.502 us; speedup vs baseline: 1.1987x; 1.1987x over previous
//
#include <hip/hip_runtime.h>
#include <hip/hip_bf16.h>
#include <stdint.h>

#define NB 8
#define NS 1024
#define DM 768
#define NH 12
#define DH 64
#define NE 2304            // 3*DM
#define MTOT (NB*NS)       // 8192

typedef unsigned short u16;
typedef __attribute__((ext_vector_type(8))) __bf16 bf16x8;
typedef __attribute__((ext_vector_type(4))) float floatx4;
typedef __attribute__((ext_vector_type(4))) uint32_t uint32x4;

// ---- workspace layout (bytes) ----
#define WS_XB  0ull                    // x bf16 [8192][768]
#define WS_WT  12582912ull             // w^T bf16 [2304][768]
#define WS_QB  16121856ull             // Q bf16 [96][1024][64] (pre-scaled by QSC)
#define WS_KB  28704768ull             // K bf16 [96][1024][64]
#define WS_VT  41287680ull             // V^T bf16 [96][64][1024]

#define QSC 0.05206490030275093f       // 768^-0.5 * log2(e)

__device__ __forceinline__ u16 f2bf(float f) {
  union { float f; uint32_t u; } v; v.f = f;
  uint32_t r = (v.u + 0x7fffu + ((v.u >> 16) & 1u)) >> 16;   // RNE
  return (u16)r;
}

__device__ __forceinline__ void gload16(const void* g, void* l) {
  __builtin_amdgcn_global_load_lds(
      (const __attribute__((address_space(1))) void*)g,
      (__attribute__((address_space(3))) void*)l, 16, 0, 0);
}

// ---------------- convert x -> bf16 ----------------
__global__ void conv_x_kernel(const float4* __restrict__ x, u16* __restrict__ xb, int n4) {
  int i = blockIdx.x * blockDim.x + threadIdx.x;
  int stride = gridDim.x * blockDim.x;
  for (; i < n4; i += stride) {
    float4 v = x[i];
    ushort4 r;
    r.x = f2bf(v.x); r.y = f2bf(v.y); r.z = f2bf(v.z); r.w = f2bf(v.w);
    ((ushort4*)xb)[i] = r;
  }
}

// ---------------- transpose w [768][2304] f32 -> [2304][768] bf16 ----------------
__global__ void transpose_w_kernel(const float* __restrict__ w, u16* __restrict__ wt) {
  __shared__ float tile[32][33];
  const int e0 = blockIdx.x * 32, k0 = blockIdx.y * 32;
  const int tx = threadIdx.x, ty = threadIdx.y;   // block (32,8)
#pragma unroll
  for (int i = 0; i < 4; i++)
    tile[ty + i*8][tx] = w[(size_t)(k0 + ty + i*8) * NE + e0 + tx];
  __syncthreads();
#pragma unroll
  for (int i = 0; i < 4; i++)
    wt[(size_t)(e0 + ty + i*8) * DM + k0 + tx] = f2bf(tile[tx][ty + i*8]);
}

// ---------------- QKV GEMM + scatter (Q pre-scaled by QSC) ----------------
__global__ __launch_bounds__(256) void qkv_gemm_kernel(
    const u16* __restrict__ xb, const u16* __restrict__ wt,
    const float* __restrict__ bias,
    u16* __restrict__ qb, u16* __restrict__ kb, u16* __restrict__ vtb) {
  __shared__ __align__(16) u16 a_lds[128 * 32];
  __shared__ __align__(16) u16 b_lds[128 * 32];
  const int t  = threadIdx.x;
  const int w  = t >> 6, l = t & 63;
  const int wr = w >> 1, wc = w & 1;
  const int lq = l & 15, lg = l >> 4;
  const int m0 = (int)(blockIdx.x % 64) * 128;
  const int n0 = (int)(blockIdx.x / 64) * 128;

  floatx4 z = {0.f, 0.f, 0.f, 0.f};
  floatx4 acc[4][4];
#pragma unroll
  for (int i = 0; i < 4; i++)
#pragma unroll
    for (int j = 0; j < 4; j++) acc[i][j] = z;

  const int srow = t >> 2;
  const int scb  = (t & 3) ^ ((t >> 3) & 3);
  const u16* ga = xb + (size_t)m0 * DM + scb * 8;
  const u16* gb = wt + (size_t)n0 * DM + scb * 8;
  const int rswz = (lq >> 1) & 3;

  for (int k0 = 0; k0 < DM; k0 += 32) {
#pragma unroll
    for (int i = 0; i < 2; i++) {
      gload16(ga + (size_t)(i*64 + srow) * DM + k0, (char*)a_lds + i*4096 + w*1024);
      gload16(gb + (size_t)(i*64 + srow) * DM + k0, (char*)b_lds + i*4096 + w*1024);
    }
    __syncthreads();

    bf16x8 af[4], bfr[4];
#pragma unroll
    for (int i = 0; i < 4; i++)
      af[i] = *(const bf16x8*)((const char*)a_lds + (wr*64 + i*16 + lq)*64 + ((lg ^ rswz) * 16));
#pragma unroll
    for (int j = 0; j < 4; j++)
      bfr[j] = *(const bf16x8*)((const char*)b_lds + (wc*64 + j*16 + lq)*64 + ((lg ^ rswz) * 16));
#pragma unroll
    for (int i = 0; i < 4; i++)
#pragma unroll
      for (int j = 0; j < 4; j++)
        acc[i][j] = __builtin_amdgcn_mfma_f32_16x16x32_bf16(af[i], bfr[j], acc[i][j], 0, 0, 0);
    __syncthreads();
  }

#pragma unroll
  for (int j = 0; j < 4; j++) {
    const int gn = n0 + wc*64 + j*16 + lq;
    const float bv = bias[gn];
    const int qkv = gn % 3;
    const int h   = gn / 192;
    const int d   = (gn % 192) / 3;
#pragma unroll
    for (int i = 0; i < 4; i++) {
      const int gmb = m0 + wr*64 + i*16 + lg*4;
#pragma unroll
      for (int r = 0; r < 4; r++) {
        const int gm = gmb + r;
        const int bb = gm >> 10, nn = gm & 1023;
        const int bh = bb * NH + h;
        float ov = acc[i][j][r] + bv;
        if (qkv == 0) ov *= QSC;
        const u16 val = f2bf(ov);
        if (qkv == 0)      qb[((size_t)bh * NS + nn) * DH + d] = val;
        else if (qkv == 1) kb[((size_t)bh * NS + nn) * DH + d] = val;
        else               vtb[((size_t)bh * DH + d) * NS + nn] = val;
      }
    }
  }
}

// ---------------- flash attention ----------------
// Round-1-proven staging (single buffer, 2 barriers, ^(row&7) swizzle).
// New algebra: S^T = mfma(K,Q) with PERMUTED key rows so each lane directly
// holds P[q=lq][keys 8*lg..8*lg+7] (the PV A-fragment) -- no P LDS round-trip.
// Defer-max softmax (m=4, THR=8); lsum reduced once in epilogue.
__global__ __launch_bounds__(256) void attn_kernel(
    const u16* __restrict__ qb, const u16* __restrict__ kb,
    const u16* __restrict__ vtb, float* __restrict__ out) {
  __shared__ __align__(16) u16 k_lds[64 * 64];
  __shared__ __align__(16) u16 v_lds[64 * 64];

  const int t = threadIdx.x, w = t >> 6, l = t & 63;
  const int bh = blockIdx.x >> 3, qblk = blockIdx.x & 7;
  const int bb = bh / NH, h = bh % NH;
  const int q0 = qblk * 128 + w * 32;
  const int lq = l & 15, lg = l >> 4;

  // Q fragments (pre-scaled by QSC in GEMM epilogue)
  bf16x8 qf[2][2];
#pragma unroll
  for (int qt = 0; qt < 2; qt++) {
    const u16* qrow = qb + ((size_t)bh * NS + q0 + qt*16 + lq) * DH;
#pragma unroll
    for (int ds = 0; ds < 2; ds++)
      qf[qt][ds] = *(const bf16x8*)&qrow[lg*8 + ds*32];
  }

  float m2[2]    = {4.0f, 4.0f};
  float lsumP[2] = {0.f, 0.f};
  floatx4 z = {0.f, 0.f, 0.f, 0.f};
  floatx4 o[2][4];
#pragma unroll
  for (int qt = 0; qt < 2; qt++)
#pragma unroll
    for (int dt = 0; dt < 4; dt++) o[qt][dt] = z;

  // staging coords (round-1 proven): row = i*32 + t/8, block = (t&7) ^ (row&7)
  const int srow = t >> 3;
  const int scb  = (t & 7) ^ (srow & 7);

  for (int kt0 = 0; kt0 < 16; kt0++) {
    const int k0 = kt0 * 64;
    __syncthreads();   // all waves done reading previous tile
#pragma unroll
    for (int i = 0; i < 2; i++) {
      const int row = i*32 + srow;
      gload16(kb  + ((size_t)bh * NS + k0 + row) * DH + scb*8, (char*)k_lds + i*4096 + w*1024);
      gload16(vtb + ((size_t)bh * DH + row) * NS + k0 + scb*8, (char*)v_lds + i*4096 + w*1024);
    }
    __syncthreads();   // vmcnt drained by barrier

#pragma unroll
    for (int half = 0; half < 2; half++) {
      // K fragments, PERMUTED key rows: lane supplies A-row lq <- key perm(lq)
      // perm(m) = (m>>2)*8 + kt*4 + (m&3); C-row cr then maps to key 8*(cr>>2)+kt*4+(cr&3)
      bf16x8 kf[2][2];
#pragma unroll
      for (int kt = 0; kt < 2; kt++) {
        const int krow = half*32 + ((lq >> 2) << 3) + kt*4 + (lq & 3);
#pragma unroll
        for (int ds = 0; ds < 2; ds++)
          kf[kt][ds] = *(const bf16x8*)((const char*)k_lds + krow*128 + ((ds*4 + lg) ^ (krow & 7))*16);
      }
      // V fragments: B[k=key half*32+8*lg+j][d=dt*16+lq]
      bf16x8 vf[4];
#pragma unroll
      for (int dt = 0; dt < 4; dt++) {
        const int vrow = dt*16 + lq;
        vf[dt] = *(const bf16x8*)((const char*)v_lds + vrow*128 + ((half*4 + lg) ^ (vrow & 7))*16);
      }

#pragma unroll
      for (int qt = 0; qt < 2; qt++) {
        floatx4 st0 = z, st1 = z;
        st0 = __builtin_amdgcn_mfma_f32_16x16x32_bf16(kf[0][0], qf[qt][0], st0, 0, 0, 0);
        st0 = __builtin_amdgcn_mfma_f32_16x16x32_bf16(kf[0][1], qf[qt][1], st0, 0, 0, 0);
        st1 = __builtin_amdgcn_mfma_f32_16x16x32_bf16(kf[1][0], qf[qt][0], st1, 0, 0, 0);
        st1 = __builtin_amdgcn_mfma_f32_16x16x32_bf16(kf[1][1], qf[qt][1], st1, 0, 0, 0);

        // lane holds S[q=lq][key 8*lg + e]: e=0..3 from st0 (kt=0), e=4..7 from st1
        float p[8];
#pragma unroll
        for (int r = 0; r < 4; r++) { p[r] = st0[r]; p[4 + r] = st1[r]; }
        const float pmax = fmaxf(fmaxf(fmaxf(p[0], p[1]), fmaxf(p[2], p[3])),
                                 fmaxf(fmaxf(p[4], p[5]), fmaxf(p[6], p[7])));

        if (!__all(pmax - m2[qt] <= 8.0f)) {    // rare: full reduce + rescale
          float mt = pmax;
          mt = fmaxf(mt, __shfl_xor(mt, 16));
          mt = fmaxf(mt, __shfl_xor(mt, 32));
          const float mnew = fmaxf(m2[qt], mt);
          const float corr = exp2f(m2[qt] - mnew);
          lsumP[qt] *= corr;
          float cr[4];
#pragma unroll
          for (int r = 0; r < 4; r++) cr[r] = __shfl(corr, lg*4 + r);
#pragma unroll
          for (int dt = 0; dt < 4; dt++)
#pragma unroll
            for (int r = 0; r < 4; r++) o[qt][dt][r] *= cr[r];
          m2[qt] = mnew;
        }

        const float m = m2[qt];
        float ls = 0.f;
        u16 pb[8];
#pragma unroll
        for (int e = 0; e < 8; e++) {
          const float pe = exp2f(p[e] - m);
          ls += pe;
          pb[e] = f2bf(pe);
        }
        lsumP[qt] += ls;

        uint32x4 pw;
        pw.x = (uint32_t)pb[0] | ((uint32_t)pb[1] << 16);
        pw.y = (uint32_t)pb[2] | ((uint32_t)pb[3] << 16);
        pw.z = (uint32_t)pb[4] | ((uint32_t)pb[5] << 16);
        pw.w = (uint32_t)pb[6] | ((uint32_t)pb[7] << 16);
        const bf16x8 pa = __builtin_bit_cast(bf16x8, pw);

#pragma unroll
        for (int dt = 0; dt < 4; dt++)
          o[qt][dt] = __builtin_amdgcn_mfma_f32_16x16x32_bf16(pa, vf[dt], o[qt][dt], 0, 0, 0);
      }
    }
  }

  // epilogue: reduce lsum (once), normalize, store fp32
#pragma unroll
  for (int qt = 0; qt < 2; qt++) {
    float ls = lsumP[qt];
    ls += __shfl_xor(ls, 16);
    ls += __shfl_xor(ls, 32);
    const float inv = 1.0f / ls;
    float ir[4];
#pragma unroll
    for (int r = 0; r < 4; r++) ir[r] = __shfl(inv, lg*4 + r);
#pragma unroll
    for (int dt = 0; dt < 4; dt++)
#pragma unroll
      for (int r = 0; r < 4; r++) {
        const int n = q0 + qt*16 + lg*4 + r;
        out[((size_t)bb * NS + n) * DM + h*DH + dt*16 + lq] = o[qt][dt][r] * ir[r];
      }
  }
}

extern "C" void kernel_launch(void* const* d_in, const int* in_sizes, int n_in,
                              void* d_out, int out_size, void* d_ws, size_t ws_size,
                              hipStream_t stream) {
  const float* x     = (const float*)d_in[0];
  const float* w_qkv = (const float*)d_in[1];
  const float* b_qkv = (const float*)d_in[2];
  float* out = (float*)d_out;
  char* ws = (char*)d_ws;

  u16* xb  = (u16*)(ws + WS_XB);
  u16* wt  = (u16*)(ws + WS_WT);
  u16* qb  = (u16*)(ws + WS_QB);
  u16* kb  = (u16*)(ws + WS_KB);
  u16* vtb = (u16*)(ws + WS_VT);

  conv_x_kernel<<<1024, 256, 0, stream>>>((const float4*)x, xb, MTOT * DM / 4);
  transpose_w_kernel<<<dim3(NE/32, DM/32), dim3(32, 8), 0, stream>>>(w_qkv, wt);
  qkv_gemm_kernel<<<64 * (NE/128), 256, 0, stream>>>(xb, wt, b_qkv, qb, kb, vtb);
  attn_kernel<<<(NB*NH) * (NS/128), 256, 0, stream>>>(qb, kb, vtb, out);
}